// Round 2
// baseline (962.838 us; speedup 1.0000x reference)
//
#include <hip/hip_runtime.h>

typedef unsigned short u16;
typedef __attribute__((ext_vector_type(8))) short short8;
typedef __attribute__((ext_vector_type(4))) float f32x4;

#define BATCH 256
#define S_LEN 100
#define EMB   1024
#define NHEAD 16
#define HDIM  64

__device__ __forceinline__ float b2f(u16 h) {
  union { unsigned u; float f; } v; v.u = ((unsigned)h) << 16; return v.f;
}
__device__ __forceinline__ u16 f2bf(float f) {
  union { float f; unsigned u; } v; v.f = f;
  unsigned r = v.u + 0x7fffu + ((v.u >> 16) & 1u);
  return (u16)(r >> 16);
}

__device__ __forceinline__ void gld_lds16(const u16* g, u16* l) {
  __builtin_amdgcn_global_load_lds((const __attribute__((address_space(1))) void*)g,
                                   (__attribute__((address_space(3))) void*)l,
                                   16, 0, 0);
}

// ---------------------------------------------------------------------------
// Weight transpose+cast: W[k][n] (1024x1024 f32) -> Wt[n][k] bf16. grid(16,16,4)
// ---------------------------------------------------------------------------
__global__ __launch_bounds__(256) void w_xpose(
    const float* __restrict__ Wq, const float* __restrict__ Wk,
    const float* __restrict__ Wv, const float* __restrict__ Wo,
    u16* __restrict__ WtQ, u16* __restrict__ WtK,
    u16* __restrict__ WtV, u16* __restrict__ WtO)
{
  __shared__ u16 tile[64 * 72];
  int z = blockIdx.z;
  const float* W = (z == 0) ? Wq : (z == 1) ? Wk : (z == 2) ? Wv : Wo;
  u16* Wt        = (z == 0) ? WtQ : (z == 1) ? WtK : (z == 2) ? WtV : WtO;
  int k0 = blockIdx.x * 64, n0 = blockIdx.y * 64;
  for (int idx = threadIdx.x; idx < 4096; idx += 256) {
    int r = idx >> 6, c = idx & 63;
    tile[r * 72 + c] = f2bf(W[(size_t)(k0 + r) * EMB + n0 + c]);
  }
  __syncthreads();
  for (int idx = threadIdx.x; idx < 4096; idx += 256) {
    int c = idx >> 6, r = idx & 63;
    Wt[(size_t)(n0 + c) * EMB + k0 + r] = tile[r * 72 + c];
  }
}

// ---------------------------------------------------------------------------
// x [B][E][S] f32 -> xT [B][S][E] bf16, adding pos_encoding[s][e] f32. grid(16,B)
// ---------------------------------------------------------------------------
__global__ __launch_bounds__(256) void xpose_pos(
    const float* __restrict__ x, const float* __restrict__ pos, u16* __restrict__ xT)
{
  __shared__ float tile[64 * 104];
  int e0 = blockIdx.x * 64;
  int b  = blockIdx.y;
  const float* xb = x + (size_t)b * EMB * S_LEN;
  for (int idx = threadIdx.x; idx < 6400; idx += 256) {
    int i = idx / 100, s = idx - i * 100;
    tile[i * 104 + s] = xb[(size_t)(e0 + i) * S_LEN + s];
  }
  __syncthreads();
  for (int idx = threadIdx.x; idx < 6400; idx += 256) {
    int s = idx >> 6, i = idx & 63;
    float v = tile[i * 104 + s] + pos[(size_t)s * EMB + e0 + i];
    xT[(size_t)b * (S_LEN * EMB) + (size_t)s * EMB + e0 + i] = f2bf(v);
  }
}

// ---------------------------------------------------------------------------
// tmp [B][S][E] bf16 -> out [B][E][S] f32.  grid (16, B)
// ---------------------------------------------------------------------------
__global__ __launch_bounds__(256) void out_xpose(
    const u16* __restrict__ tmp, float* __restrict__ out)
{
  __shared__ u16 tile[100 * 72];
  int e0 = blockIdx.x * 64;
  int b  = blockIdx.y;
  for (int idx = threadIdx.x; idx < 6400; idx += 256) {
    int s = idx >> 6, i = idx & 63;
    tile[s * 72 + i] = tmp[(size_t)b * (S_LEN * EMB) + (size_t)s * EMB + e0 + i];
  }
  __syncthreads();
  for (int idx = threadIdx.x; idx < 6400; idx += 256) {
    int i = idx / 100, s = idx - i * 100;
    out[((size_t)b * EMB + e0 + i) * S_LEN + s] = b2f(tile[s * 72 + i]);
  }
}

// ---------------------------------------------------------------------------
// GEMM: C = A @ Bt^T + bias.  A [M][K] bf16, Bt [N][K] bf16, C [M][N] bf16,
// bias f32.  128x128 tile, BK=64, 16x16x32 bf16 MFMA, 4 waves 4x4 subtiles.
// blockIdx.z selects one of three (Bt, bias, C) sets (fused QKV).
// ---------------------------------------------------------------------------
__global__ __launch_bounds__(256) void gemm_bt(
    const u16* __restrict__ A,
    const u16* __restrict__ Bt0, const u16* __restrict__ Bt1, const u16* __restrict__ Bt2,
    const float* __restrict__ bias0, const float* __restrict__ bias1, const float* __restrict__ bias2,
    u16* __restrict__ C0, u16* __restrict__ C1, u16* __restrict__ C2,
    int Kd, int Nd)
{
  __shared__ u16 lA[128 * 64];
  __shared__ u16 lB[128 * 64];
  int z = blockIdx.z;
  const u16* Bt     = (z == 0) ? Bt0 : (z == 1) ? Bt1 : Bt2;
  const float* bias = (z == 0) ? bias0 : (z == 1) ? bias1 : bias2;
  u16* C            = (z == 0) ? C0 : (z == 1) ? C1 : C2;

  const int tid  = threadIdx.x;
  const int wave = tid >> 6, lane = tid & 63;
  const int quad = lane >> 4, l16 = lane & 15;
  const int m0 = blockIdx.x * 128, n0 = blockIdx.y * 128;
  const int wm = (wave >> 1) * 64, wn = (wave & 1) * 64;

  f32x4 acc[4][4] = {};

  for (int k0 = 0; k0 < Kd; k0 += 64) {
#pragma unroll
    for (int i = 0; i < 4; ++i) {
      int chunk = (i * 4 + wave) * 64 + lane;   // 0..1023, lane-contiguous per wave
      int row = chunk >> 3, c8 = (chunk & 7) << 3;
      gld_lds16(A  + (size_t)(m0 + row) * Kd + k0 + c8, lA + (i * 4 + wave) * 512);
      gld_lds16(Bt + (size_t)(n0 + row) * Kd + k0 + c8, lB + (i * 4 + wave) * 512);
    }
    __syncthreads();
#pragma unroll
    for (int kk = 0; kk < 64; kk += 32) {
      short8 af[4], bf[4];
#pragma unroll
      for (int mi = 0; mi < 4; ++mi)
        af[mi] = *(const short8*)(lA + (wm + mi * 16 + l16) * 64 + kk + quad * 8);
#pragma unroll
      for (int ni = 0; ni < 4; ++ni)
        bf[ni] = *(const short8*)(lB + (wn + ni * 16 + l16) * 64 + kk + quad * 8);
#pragma unroll
      for (int mi = 0; mi < 4; ++mi)
#pragma unroll
        for (int ni = 0; ni < 4; ++ni)
          acc[mi][ni] = __builtin_amdgcn_mfma_f32_16x16x32_bf16(af[mi], bf[ni], acc[mi][ni], 0, 0, 0);
    }
    __syncthreads();
  }

#pragma unroll
  for (int ni = 0; ni < 4; ++ni) {
    int col = n0 + wn + ni * 16 + l16;
    float bv = bias[col];
#pragma unroll
    for (int mi = 0; mi < 4; ++mi) {
#pragma unroll
      for (int r = 0; r < 4; ++r) {
        int row = m0 + wm + mi * 16 + quad * 4 + r;
        C[(size_t)row * Nd + col] = f2bf(acc[mi][ni][r] + bv);
      }
    }
  }
}

// ---------------------------------------------------------------------------
// Attention: one block per (b,h).  Q,K,V [B*S][EMB] bf16, head slice h*64.
// scores = q k^T / 8 -> softmax -> attn out (f32) + attended [B*S][EMB] bf16.
// ---------------------------------------------------------------------------
__global__ __launch_bounds__(256) void attn_kernel(
    const u16* __restrict__ Q, const u16* __restrict__ Kb, const u16* __restrict__ V,
    float* __restrict__ attn_out, u16* __restrict__ attended)
{
  __shared__ u16  sQK[112 * 64 * 2];   // q tile then k tile; later overlaid by P [112][128]
  __shared__ u16  sVt[64 * 128];       // V^T: [d][s], s cols >=100 zeroed
  __shared__ float sS[100 * 112];      // fp32 scores, rows 0..99

  u16* sQ = sQK;
  u16* sK = sQK + 112 * 64;
  u16* sP = sQK;                       // P overlays q+k after softmax

  const int bh = blockIdx.x;
  const int b = bh >> 4, h = bh & 15;
  const int tid = threadIdx.x;
  const int wave = tid >> 6, lane = tid & 63;
  const int quad = lane >> 4, l16 = lane & 15;
  const size_t qbase = (size_t)b * S_LEN * EMB + h * HDIM;

  // zero V^T and the q/k pad rows (100..111); stage q and k (16B chunks)
  for (int i = tid; i < 64 * 128 / 2; i += 256) ((unsigned*)sVt)[i] = 0u;
  for (int i = tid; i < 768; i += 256) { sQ[6400 + i] = 0; sK[6400 + i] = 0; }
  for (int c = tid; c < 800; c += 256) {
    int s = c >> 3, d0 = (c & 7) << 3;
    *(uint4*)(sQ + s * 64 + d0) = *(const uint4*)(Q  + qbase + (size_t)s * EMB + d0);
    *(uint4*)(sK + s * 64 + d0) = *(const uint4*)(Kb + qbase + (size_t)s * EMB + d0);
  }
  __syncthreads();

  // scatter v into V^T [d][128]
  for (int c = tid; c < 800; c += 256) {
    int s = c >> 3, d0 = (c & 7) << 3;
    uint4 v8 = *(const uint4*)(V + qbase + (size_t)s * EMB + d0);
    const u16* p = (const u16*)&v8;
#pragma unroll
    for (int j = 0; j < 8; ++j) sVt[(d0 + j) * 128 + s] = p[j];
  }

  // QK^T: M=112 (7 tiles) x N=112 (7 tiles), K=64
  for (int t = wave; t < 49; t += 4) {
    int mi = t / 7, ni = t - mi * 7;
    f32x4 acc = {0.f, 0.f, 0.f, 0.f};
#pragma unroll
    for (int kk = 0; kk < 64; kk += 32) {
      short8 a  = *(const short8*)(sQ + (mi * 16 + l16) * 64 + kk + quad * 8);
      short8 bb = *(const short8*)(sK + (ni * 16 + l16) * 64 + kk + quad * 8);
      acc = __builtin_amdgcn_mfma_f32_16x16x32_bf16(a, bb, acc, 0, 0, 0);
    }
    int col = ni * 16 + l16;
#pragma unroll
    for (int r = 0; r < 4; ++r) {
      int row = mi * 16 + quad * 4 + r;
      if (row < S_LEN) sS[row * 112 + col] = acc[r] * 0.125f;
    }
  }
  __syncthreads();

  // row softmax (threads 0..99): write f32 attn output + bf16 P (clobbers q/k)
  if (tid < S_LEN) {
    float* Srow = sS + tid * 112;
    float mx = -1e30f;
    for (int c = 0; c < S_LEN; ++c) mx = fmaxf(mx, Srow[c]);
    float sum = 0.f;
    for (int c = 0; c < S_LEN; ++c) { float e = __expf(Srow[c] - mx); Srow[c] = e; sum += e; }
    float inv = 1.f / sum;
    u16* Prow = sP + tid * 128;
    size_t ao = (size_t)bh * (S_LEN * S_LEN) + (size_t)tid * S_LEN;
    for (int c = 0; c < S_LEN; ++c) {
      float p = Srow[c] * inv;
      Prow[c] = f2bf(p);
      attn_out[ao + c] = p;
    }
    for (int c = S_LEN; c < 128; ++c) Prow[c] = 0;
  }
  __syncthreads();

  // PV: M=112 (7 tiles) x N=64 (4 tiles), K=128 (cols >=100 zero)
  for (int t = wave; t < 28; t += 4) {
    int mi = t >> 2, ni = t & 3;
    f32x4 acc = {0.f, 0.f, 0.f, 0.f};
#pragma unroll
    for (int kk = 0; kk < 128; kk += 32) {
      short8 a  = *(const short8*)(sP  + (mi * 16 + l16) * 128 + kk + quad * 8);
      short8 bb = *(const short8*)(sVt + (ni * 16 + l16) * 128 + kk + quad * 8);
      acc = __builtin_amdgcn_mfma_f32_16x16x32_bf16(a, bb, acc, 0, 0, 0);
    }
    int col = ni * 16 + l16;
#pragma unroll
    for (int r = 0; r < 4; ++r) {
      int row = mi * 16 + quad * 4 + r;
      if (row < S_LEN)
        attended[((size_t)b * S_LEN + row) * EMB + h * HDIM + col] = f2bf(acc[r]);
    }
  }
}

// ---------------------------------------------------------------------------
extern "C" void kernel_launch(void* const* d_in, const int* in_sizes, int n_in,
                              void* d_out, int out_size, void* d_ws, size_t ws_size,
                              hipStream_t stream) {
  const float* x   = (const float*)d_in[0];
  const float* Wq  = (const float*)d_in[1];
  const float* bq  = (const float*)d_in[2];
  const float* Wk  = (const float*)d_in[3];
  const float* bk  = (const float*)d_in[4];
  const float* Wv  = (const float*)d_in[5];
  const float* bv  = (const float*)d_in[6];
  const float* Wo  = (const float*)d_in[7];
  const float* bo  = (const float*)d_in[8];
  const float* pos = (const float*)d_in[9];

  float* out  = (float*)d_out;                     // [B][E][S] = 26,214,400 f32
  float* attn = out + (size_t)BATCH * EMB * S_LEN; // [B][H][S][S] = 40,960,000 f32

  const size_t MTOT = (size_t)BATCH * S_LEN;       // 25600
  u16* ws   = (u16*)d_ws;
  u16* xT   = ws;                                  // [25600][1024] bf16
  u16* Qb   = ws + MTOT * EMB;
  u16* Kbuf = ws + 2 * MTOT * EMB;
  u16* Vb   = ws + 3 * MTOT * EMB;
  u16* WtQ  = ws + 4 * MTOT * EMB;
  u16* WtK  = WtQ + (size_t)EMB * EMB;
  u16* WtV  = WtK + (size_t)EMB * EMB;
  u16* WtO  = WtV + (size_t)EMB * EMB;
  u16* attended = xT;                              // reuse (xT dead after QKV gemm)
  u16* tmp      = Qb;                              // reuse (Q dead after attention)

  w_xpose<<<dim3(16, 16, 4), 256, 0, stream>>>(Wq, Wk, Wv, Wo, WtQ, WtK, WtV, WtO);
  xpose_pos<<<dim3(16, BATCH), 256, 0, stream>>>(x, pos, xT);
  gemm_bt<<<dim3(200, 8, 3), 256, 0, stream>>>(xT, WtQ, WtK, WtV, bq, bk, bv,
                                               Qb, Kbuf, Vb, EMB, EMB);
  attn_kernel<<<dim3(BATCH * NHEAD), 256, 0, stream>>>(Qb, Kbuf, Vb, attn, attended);
  gemm_bt<<<dim3(200, 8, 1), 256, 0, stream>>>(attended, WtO, WtO, WtO, bo, bo, bo,
                                               tmp, tmp, tmp, EMB, EMB);
  out_xpose<<<dim3(16, BATCH), 256, 0, stream>>>(tmp, out);
}

// Round 3
// 832.273 us; speedup vs baseline: 1.1569x; 1.1569x over previous
//
#include <hip/hip_runtime.h>

typedef unsigned short u16;
typedef __attribute__((ext_vector_type(8))) short short8;
typedef __attribute__((ext_vector_type(4))) float f32x4;

#define BATCH 256
#define S_LEN 100
#define EMB   1024
#define NHEAD 16
#define HDIM  64

__device__ __forceinline__ float b2f(u16 h) {
  union { unsigned u; float f; } v; v.u = ((unsigned)h) << 16; return v.f;
}
__device__ __forceinline__ u16 f2bf(float f) {
  union { float f; unsigned u; } v; v.f = f;
  unsigned r = v.u + 0x7fffu + ((v.u >> 16) & 1u);
  return (u16)(r >> 16);
}

__device__ __forceinline__ void gld_lds16(const u16* g, u16* l) {
  __builtin_amdgcn_global_load_lds((const __attribute__((address_space(1))) void*)g,
                                   (__attribute__((address_space(3))) void*)l,
                                   16, 0, 0);
}

// ---------------------------------------------------------------------------
// Weight transpose+cast: W[k][n] (1024x1024 f32) -> Wt[n][k] bf16. grid(16,16,4)
// ---------------------------------------------------------------------------
__global__ __launch_bounds__(256) void w_xpose(
    const float* __restrict__ Wq, const float* __restrict__ Wk,
    const float* __restrict__ Wv, const float* __restrict__ Wo,
    u16* __restrict__ WtQ, u16* __restrict__ WtK,
    u16* __restrict__ WtV, u16* __restrict__ WtO)
{
  __shared__ u16 tile[64 * 72];
  int z = blockIdx.z;
  const float* W = (z == 0) ? Wq : (z == 1) ? Wk : (z == 2) ? Wv : Wo;
  u16* Wt        = (z == 0) ? WtQ : (z == 1) ? WtK : (z == 2) ? WtV : WtO;
  int k0 = blockIdx.x * 64, n0 = blockIdx.y * 64;
  for (int idx = threadIdx.x; idx < 4096; idx += 256) {
    int r = idx >> 6, c = idx & 63;
    tile[r * 72 + c] = f2bf(W[(size_t)(k0 + r) * EMB + n0 + c]);
  }
  __syncthreads();
  for (int idx = threadIdx.x; idx < 4096; idx += 256) {
    int c = idx >> 6, r = idx & 63;
    Wt[(size_t)(n0 + c) * EMB + k0 + r] = tile[r * 72 + c];
  }
}

// ---------------------------------------------------------------------------
// x [B][E][S] f32 -> xT [B][S][E] bf16, adding pos_encoding[s][e] f32. grid(16,B)
// ---------------------------------------------------------------------------
__global__ __launch_bounds__(256) void xpose_pos(
    const float* __restrict__ x, const float* __restrict__ pos, u16* __restrict__ xT)
{
  __shared__ float tile[64 * 104];
  int e0 = blockIdx.x * 64;
  int b  = blockIdx.y;
  const float* xb = x + (size_t)b * EMB * S_LEN;
  for (int idx = threadIdx.x; idx < 6400; idx += 256) {
    int i = idx / 100, s = idx - i * 100;
    tile[i * 104 + s] = xb[(size_t)(e0 + i) * S_LEN + s];
  }
  __syncthreads();
  for (int idx = threadIdx.x; idx < 6400; idx += 256) {
    int s = idx >> 6, i = idx & 63;
    float v = tile[i * 104 + s] + pos[(size_t)s * EMB + e0 + i];
    xT[(size_t)b * (S_LEN * EMB) + (size_t)s * EMB + e0 + i] = f2bf(v);
  }
}

// ---------------------------------------------------------------------------
// tmp [B][S][E] bf16 -> out [B][E][S] f32.  grid (16, B)
// ---------------------------------------------------------------------------
__global__ __launch_bounds__(256) void out_xpose(
    const u16* __restrict__ tmp, float* __restrict__ out)
{
  __shared__ u16 tile[100 * 72];
  int e0 = blockIdx.x * 64;
  int b  = blockIdx.y;
  for (int idx = threadIdx.x; idx < 6400; idx += 256) {
    int s = idx >> 6, i = idx & 63;
    tile[s * 72 + i] = tmp[(size_t)b * (S_LEN * EMB) + (size_t)s * EMB + e0 + i];
  }
  __syncthreads();
  for (int idx = threadIdx.x; idx < 6400; idx += 256) {
    int i = idx / 100, s = idx - i * 100;
    out[((size_t)b * EMB + e0 + i) * S_LEN + s] = b2f(tile[s * 72 + i]);
  }
}

// ---------------------------------------------------------------------------
// GEMM: C = A @ Bt^T + bias.  XOR-swizzled LDS: chunk (row,c8) of the 128x64
// tile lives at LDS slot row*64 + ((c8 ^ (row&7))*8) -> fragment ds_read_b128
// banks spread by row&7 (2-way, free) instead of 16-way.
// ---------------------------------------------------------------------------
__global__ __launch_bounds__(256) void gemm_bt(
    const u16* __restrict__ A,
    const u16* __restrict__ Bt0, const u16* __restrict__ Bt1, const u16* __restrict__ Bt2,
    const float* __restrict__ bias0, const float* __restrict__ bias1, const float* __restrict__ bias2,
    u16* __restrict__ C0, u16* __restrict__ C1, u16* __restrict__ C2,
    int Kd, int Nd)
{
  __shared__ u16 lA[128 * 64];
  __shared__ u16 lB[128 * 64];
  int z = blockIdx.z;
  const u16* Bt     = (z == 0) ? Bt0 : (z == 1) ? Bt1 : Bt2;
  const float* bias = (z == 0) ? bias0 : (z == 1) ? bias1 : bias2;
  u16* C            = (z == 0) ? C0 : (z == 1) ? C1 : C2;

  const int tid  = threadIdx.x;
  const int wave = tid >> 6, lane = tid & 63;
  const int quad = lane >> 4, l16 = lane & 15;
  const int m0 = blockIdx.x * 128, n0 = blockIdx.y * 128;
  const int wm = (wave >> 1) * 64, wn = (wave & 1) * 64;

  f32x4 acc[4][4] = {};

  for (int k0 = 0; k0 < Kd; k0 += 64) {
#pragma unroll
    for (int i = 0; i < 4; ++i) {
      int slot = (i * 4 + wave) * 64 + lane;        // 0..1023
      int row  = slot >> 3;
      int jg   = ((slot & 7) ^ (row & 7)) << 3;     // swizzled global chunk col
      gld_lds16(A  + (size_t)(m0 + row) * Kd + k0 + jg, lA + (i * 4 + wave) * 512);
      gld_lds16(Bt + (size_t)(n0 + row) * Kd + k0 + jg, lB + (i * 4 + wave) * 512);
    }
    __syncthreads();
#pragma unroll
    for (int kk = 0; kk < 64; kk += 32) {
      short8 af[4], bf[4];
#pragma unroll
      for (int mi = 0; mi < 4; ++mi) {
        int row = wm + mi * 16 + l16;
        af[mi] = *(const short8*)(lA + row * 64 + ((((kk >> 3) + quad) ^ (row & 7)) << 3));
      }
#pragma unroll
      for (int ni = 0; ni < 4; ++ni) {
        int row = wn + ni * 16 + l16;
        bf[ni] = *(const short8*)(lB + row * 64 + ((((kk >> 3) + quad) ^ (row & 7)) << 3));
      }
#pragma unroll
      for (int mi = 0; mi < 4; ++mi)
#pragma unroll
        for (int ni = 0; ni < 4; ++ni)
          acc[mi][ni] = __builtin_amdgcn_mfma_f32_16x16x32_bf16(af[mi], bf[ni], acc[mi][ni], 0, 0, 0);
    }
    __syncthreads();
  }

#pragma unroll
  for (int ni = 0; ni < 4; ++ni) {
    int col = n0 + wn + ni * 16 + l16;
    float bv = bias[col];
#pragma unroll
    for (int mi = 0; mi < 4; ++mi) {
#pragma unroll
      for (int r = 0; r < 4; ++r) {
        int row = m0 + wm + mi * 16 + quad * 4 + r;
        C[(size_t)row * Nd + col] = f2bf(acc[mi][ni][r] + bv);
      }
    }
  }
}

// ---------------------------------------------------------------------------
// Attention v2: one block per (b,h).  LDS 70.7 KB -> 2 blocks/CU.
//  sQK (28672 B): q[112x64] + k[112x64], later overlaid by P [112][128] bf16
//  smemB (42000 B): scores f32 [100][105], later overlaid by V^T u16 [64][128]
// All MFMA fragment layouts XOR-swizzled; attn_out written coalesced.
// ---------------------------------------------------------------------------
__global__ __launch_bounds__(256) void attn_kernel(
    const u16* __restrict__ Q, const u16* __restrict__ Kb, const u16* __restrict__ V,
    float* __restrict__ attn_out, u16* __restrict__ attended)
{
  __shared__ u16 sQK[112 * 64 * 2];
  __shared__ __align__(16) char smemB[100 * 105 * 4];

  u16* sQ   = sQK;
  u16* sK   = sQK + 112 * 64;
  u16* sP   = sQK;                    // overlays q+k after softmax
  float* sS = (float*)smemB;          // scores, stride 105
  u16* sVt  = (u16*)smemB;            // overlays sS after attn_out written

  const int bh = blockIdx.x;
  const int b = bh >> 4, h = bh & 15;
  const int tid = threadIdx.x;
  const int wave = tid >> 6, lane = tid & 63;
  const int quad = lane >> 4, l16 = lane & 15;
  const size_t qbase = (size_t)b * S_LEN * EMB + h * HDIM;

  // ---- preload V into registers (800 16B chunks) ----
  uint4 vr0, vr1, vr2, vr3 = make_uint4(0, 0, 0, 0);
  {
    int c0 = tid, c1 = tid + 256, c2 = tid + 512;
    vr0 = *(const uint4*)(V + qbase + (size_t)(c0 >> 3) * EMB + ((c0 & 7) << 3));
    vr1 = *(const uint4*)(V + qbase + (size_t)(c1 >> 3) * EMB + ((c1 & 7) << 3));
    vr2 = *(const uint4*)(V + qbase + (size_t)(c2 >> 3) * EMB + ((c2 & 7) << 3));
    if (tid < 32) {
      int c3 = tid + 768;
      vr3 = *(const uint4*)(V + qbase + (size_t)(c3 >> 3) * EMB + ((c3 & 7) << 3));
    }
  }

  // ---- stage q, k swizzled; zero pad rows 100..111 ----
  for (int c = tid; c < 896; c += 256) {
    int s = c >> 3, j = c & 7;
    int jg = (j ^ (s & 7)) << 3;
    uint4 qv = make_uint4(0, 0, 0, 0), kv = make_uint4(0, 0, 0, 0);
    if (s < S_LEN) {
      qv = *(const uint4*)(Q  + qbase + (size_t)s * EMB + jg);
      kv = *(const uint4*)(Kb + qbase + (size_t)s * EMB + jg);
    }
    *(uint4*)(sQ + c * 8) = qv;
    *(uint4*)(sK + c * 8) = kv;
  }
  __syncthreads();

  // ---- QK^T: 7x7 16x16 tiles, K=64, swizzled frag reads ----
  for (int t = wave; t < 49; t += 4) {
    int mi = t / 7, ni = t - mi * 7;
    f32x4 acc = {0.f, 0.f, 0.f, 0.f};
#pragma unroll
    for (int kk = 0; kk < 64; kk += 32) {
      int rq = mi * 16 + l16, rk = ni * 16 + l16;
      int cix = (kk >> 3) + quad;
      short8 a  = *(const short8*)(sQ + rq * 64 + ((cix ^ (rq & 7)) << 3));
      short8 bb = *(const short8*)(sK + rk * 64 + ((cix ^ (rk & 7)) << 3));
      acc = __builtin_amdgcn_mfma_f32_16x16x32_bf16(a, bb, acc, 0, 0, 0);
    }
    int col = ni * 16 + l16;
#pragma unroll
    for (int r = 0; r < 4; ++r) {
      int row = mi * 16 + quad * 4 + r;
      if (row < S_LEN && col < S_LEN) sS[row * 105 + col] = acc[r] * 0.125f;
    }
  }
  __syncthreads();

  // ---- zero P pad rows 100..111 (all threads) ----
  for (int i = tid; i < 192; i += 256)
    *(uint4*)(sP + (100 + (i >> 4)) * 128 + ((i & 15) << 3)) = make_uint4(0, 0, 0, 0);

  // ---- softmax: one thread per row; P stored swizzled bf16, normalized f32 kept in sS ----
  if (tid < S_LEN) {
    float* Srow = sS + tid * 105;
    int rs = tid & 7;
    float mx = -1e30f;
    for (int c = 0; c < S_LEN; ++c) mx = fmaxf(mx, Srow[c]);
    float sum = 0.f;
    for (int c = 0; c < S_LEN; ++c) { float e = __expf(Srow[c] - mx); Srow[c] = e; sum += e; }
    float inv = 1.f / sum;
    u16* Prow = sP + tid * 128;
    for (int c = 0; c < S_LEN; ++c) {
      float p = Srow[c] * inv;
      Srow[c] = p;
      Prow[(((c >> 3) ^ rs) << 3) + (c & 7)] = f2bf(p);
    }
    for (int c = S_LEN; c < 128; ++c)
      Prow[(((c >> 3) ^ rs) << 3) + (c & 7)] = 0;
  }
  __syncthreads();

  // ---- coalesced attn_out write from sS ----
  {
    float* ao = attn_out + (size_t)bh * (S_LEN * S_LEN);
    for (int i = tid; i < S_LEN * S_LEN; i += 256) {
      int r = i / 100, c = i - r * 100;
      ao[i] = sS[r * 105 + c];
    }
  }
  __syncthreads();

  // ---- build V^T over the score buffer: zero, then scatter from regs ----
  for (int i = tid; i < 1024; i += 256)
    *(uint4*)(sVt + i * 8) = make_uint4(0, 0, 0, 0);
  __syncthreads();
  {
    const u16* p0 = (const u16*)&vr0;
    const u16* p1 = (const u16*)&vr1;
    const u16* p2 = (const u16*)&vr2;
    const u16* p3 = (const u16*)&vr3;
    int c0 = tid, c1 = tid + 256, c2 = tid + 512, c3 = tid + 768;
#pragma unroll
    for (int j = 0; j < 8; ++j) {
      int s, d;
      s = c0 >> 3; d = ((c0 & 7) << 3) + j;
      sVt[d * 128 + (((s >> 3) ^ (d & 7)) << 3) + (s & 7)] = p0[j];
      s = c1 >> 3; d = ((c1 & 7) << 3) + j;
      sVt[d * 128 + (((s >> 3) ^ (d & 7)) << 3) + (s & 7)] = p1[j];
      s = c2 >> 3; d = ((c2 & 7) << 3) + j;
      sVt[d * 128 + (((s >> 3) ^ (d & 7)) << 3) + (s & 7)] = p2[j];
      if (tid < 32) {
        s = c3 >> 3; d = ((c3 & 7) << 3) + j;
        sVt[d * 128 + (((s >> 3) ^ (d & 7)) << 3) + (s & 7)] = p3[j];
      }
    }
  }
  __syncthreads();

  // ---- PV: 7x4 16x16 tiles, K=128 (cols >=100 zero), swizzled frag reads ----
  for (int t = wave; t < 28; t += 4) {
    int mi = t >> 2, ni = t & 3;
    f32x4 acc = {0.f, 0.f, 0.f, 0.f};
#pragma unroll
    for (int kk = 0; kk < 128; kk += 32) {
      int rp = mi * 16 + l16, rv = ni * 16 + l16;
      int cix = (kk >> 3) + quad;
      short8 a  = *(const short8*)(sP  + rp * 128 + ((cix ^ (rp & 7)) << 3));
      short8 bb = *(const short8*)(sVt + rv * 128 + ((cix ^ (rv & 7)) << 3));
      acc = __builtin_amdgcn_mfma_f32_16x16x32_bf16(a, bb, acc, 0, 0, 0);
    }
    int col = ni * 16 + l16;
#pragma unroll
    for (int r = 0; r < 4; ++r) {
      int row = mi * 16 + quad * 4 + r;
      if (row < S_LEN)
        attended[((size_t)b * S_LEN + row) * EMB + h * HDIM + col] = f2bf(acc[r]);
    }
  }
}

// ---------------------------------------------------------------------------
extern "C" void kernel_launch(void* const* d_in, const int* in_sizes, int n_in,
                              void* d_out, int out_size, void* d_ws, size_t ws_size,
                              hipStream_t stream) {
  const float* x   = (const float*)d_in[0];
  const float* Wq  = (const float*)d_in[1];
  const float* bq  = (const float*)d_in[2];
  const float* Wk  = (const float*)d_in[3];
  const float* bk  = (const float*)d_in[4];
  const float* Wv  = (const float*)d_in[5];
  const float* bv  = (const float*)d_in[6];
  const float* Wo  = (const float*)d_in[7];
  const float* bo  = (const float*)d_in[8];
  const float* pos = (const float*)d_in[9];

  float* out  = (float*)d_out;                     // [B][E][S] f32
  float* attn = out + (size_t)BATCH * EMB * S_LEN; // [B][H][S][S] f32

  const size_t MTOT = (size_t)BATCH * S_LEN;       // 25600
  u16* ws   = (u16*)d_ws;
  u16* xT   = ws;                                  // [25600][1024] bf16
  u16* Qb   = ws + MTOT * EMB;
  u16* Kbuf = ws + 2 * MTOT * EMB;
  u16* Vb   = ws + 3 * MTOT * EMB;
  u16* WtQ  = ws + 4 * MTOT * EMB;
  u16* WtK  = WtQ + (size_t)EMB * EMB;
  u16* WtV  = WtK + (size_t)EMB * EMB;
  u16* WtO  = WtV + (size_t)EMB * EMB;
  u16* attended = xT;                              // reuse (xT dead after QKV gemm)
  u16* tmp      = Qb;                              // reuse (Q dead after attention)

  w_xpose<<<dim3(16, 16, 4), 256, 0, stream>>>(Wq, Wk, Wv, Wo, WtQ, WtK, WtV, WtO);
  xpose_pos<<<dim3(16, BATCH), 256, 0, stream>>>(x, pos, xT);
  gemm_bt<<<dim3(200, 8, 3), 256, 0, stream>>>(xT, WtQ, WtK, WtV, bq, bk, bv,
                                               Qb, Kbuf, Vb, EMB, EMB);
  attn_kernel<<<dim3(BATCH * NHEAD), 256, 0, stream>>>(Qb, Kbuf, Vb, attn, attended);
  gemm_bt<<<dim3(200, 8, 1), 256, 0, stream>>>(attended, WtO, WtO, WtO, bo, bo, bo,
                                               tmp, tmp, tmp, EMB, EMB);
  out_xpose<<<dim3(16, BATCH), 256, 0, stream>>>(tmp, out);
}